// Round 18
// baseline (64.628 us; speedup 1.0000x reference)
//
#include <hip/hip_runtime.h>
#include <math.h>

#define D 64
#define NI 100
#define BSZ 64
#define LN_EPS 1e-5f
#define NIP 112            // padded j rows (7 tiles of 16)
#define NT2 25
#define C2L 2.8853900817779268f   // 2*log2(e)
#define TILEB 14336        // bytes per per-batch bf16 tile (NIP*64*2)

// ws layout (float indices) — proven 3.605 MB envelope (R6-R9/R12/R13/R16/R17):
#define OFF_W3GTT 0        // f32 [d][k] = w3[d,k]*g[k]            (4096)
#define OFF_W3G   8192     // f32 [64] sum_k w3[d,k]*g[k]
#define OFF_C0    8256     // f32 [64] C2L*(bij[d] + sum_k w3[d,k]*bln[k])
#define OFF_WSUMS 8320     // f32 [1] sum(wsum)
#define OFF_PB16  8448     // bf16 [6400*64] = C2L * LN(e_t).w2    (204800 f32 slots)
#define OFF_E16   213248   // 64 x TILEB: bf16 e, swizzled         (229376 floats)
#define OFF_ET16  442624   // (reserved, unused)
#define OFF_PA16  672000   // 64 x TILEB: bf16 PA [j][x][n]        (229376 floats)
// end: 901376 floats = 3.605 MB (proven)

typedef __attribute__((ext_vector_type(8))) short bf8;
typedef __attribute__((ext_vector_type(4))) float f32x4;

// raw v_exp_f32 (no OCML fixup; |arg| << 126 here)
__device__ inline float fast_exp2(float x) {
#if __has_builtin(__builtin_amdgcn_exp2f)
  return __builtin_amdgcn_exp2f(x);
#else
  float r; asm("v_exp_f32 %0, %1" : "=v"(r) : "v"(x)); return r;
#endif
}

// rounding f32->bf16
__device__ inline uint32_t f2bf(float x) {
  uint32_t u = __float_as_uint(x);
  return (u + 0x7fffu + ((u >> 16) & 1u)) >> 16;
}
__device__ inline int pk2(float a, float b) { return (int)(f2bf(a) | (f2bf(b) << 16)); }
// truncating pack (3 ops)
__device__ inline int pkt(float a, float b) {
  return (int)((__float_as_uint(a) >> 16) | (__float_as_uint(b) & 0xffff0000u));
}
// square a bf16x8 fragment, truncating round
__device__ inline bf8 sq8t(bf8 a) {
  bf8 r;
#pragma unroll
  for (int t = 0; t < 8; ++t) {
    float v = __uint_as_float(((uint32_t)(unsigned short)a[t]) << 16);
    r[t] = (short)(__float_as_uint(v * v) >> 16);
  }
  return r;
}

// K1: one block per batch b (grid 64). Tables distributed; emits E16 (swizzled
// bf16), PA16 = C2L*LNE.w1 (bf16 [j][x][n]), PB16 = C2L*LNE.w2 (bf16 [t][d]).
// (Byte-identical to the R12/R16/R17 kernel that passed.)
__global__ __launch_bounds__(256) void k1_batch(
    const float* __restrict__ emb,
    const float* __restrict__ gg,
    const float* __restrict__ bb,
    const float* __restrict__ w_ij,
    const float* __restrict__ bij,
    const float* __restrict__ wsum,
    float* __restrict__ ws) {
  int b = blockIdx.x;
  int tid = threadIdx.x;
  int wv = tid >> 6, lane = tid & 63, g = lane >> 4, c = lane & 15;

  __shared__ ushort LNE16[NIP * 64];   // 14336 B, swizzled
  char* e16g  = (char*)ws + OFF_E16  * 4 + b * TILEB;
  char* pa16g = (char*)ws + OFF_PA16 * 4 + b * TILEB;
  ushort* pb16 = (ushort*)(ws + OFF_PB16);
  const float* eb = emb + b * NI * D;

  // ---- table slice (read only by k2) ----
  if (wv == 0) {
    float w  = w_ij[b * 192 + 128 + lane];   // w3[b][k=lane]
    float gk = gg[lane];
    ws[OFF_W3GTT + b * 64 + lane] = w * gk;
    float wg = w * gk, wb = w * bb[lane];
#pragma unroll
    for (int off = 32; off > 0; off >>= 1) {
      wg += __shfl_xor(wg, off, 64);
      wb += __shfl_xor(wb, off, 64);
    }
    if (lane == 0) {
      ws[OFF_W3G + b] = wg;
      ws[OFF_C0 + b]  = C2L * (bij[b] + wb);
    }
  } else if (wv == 1 && b == 0) {
    float v = wsum[lane];
#pragma unroll
    for (int off = 32; off > 0; off >>= 1)
      v += __shfl_xor(v, off, 64);
    if (lane == 0) ws[OFF_WSUMS] = v;
  }

  // ---- stage: e -> E16(global), LN(e) -> LNE16(LDS) ----
  for (int u = tid; u < NIP * 8; u += 256) {
    int r = u >> 3, cb = u & 7, kk = cb * 8;
    int4 pe, pl;
    if (r < NI) {
      const float* sp = eb + r * 64 + kk;
      float4 f0 = *(const float4*)sp, f1 = *(const float4*)(sp + 4);
      float s  = f0.x + f0.y + f0.z + f0.w + f1.x + f1.y + f1.z + f1.w;
      float s2 = f0.x*f0.x + f0.y*f0.y + f0.z*f0.z + f0.w*f0.w
               + f1.x*f1.x + f1.y*f1.y + f1.z*f1.z + f1.w*f1.w;
#pragma unroll
      for (int off = 1; off < 8; off <<= 1) {
        s  += __shfl_xor(s, off, 64);
        s2 += __shfl_xor(s2, off, 64);
      }
      float mu  = s * (1.f / 64.f);
      float var = s2 * (1.f / 64.f) - mu * mu;
      float rsv = rsqrtf(var + LN_EPS);
      float4 g0 = *(const float4*)(gg + kk), g1v = *(const float4*)(gg + kk + 4);
      float4 b0 = *(const float4*)(bb + kk), b1v = *(const float4*)(bb + kk + 4);
      float l0 = fmaf((f0.x - mu) * rsv, g0.x, b0.x);
      float l1 = fmaf((f0.y - mu) * rsv, g0.y, b0.y);
      float l2 = fmaf((f0.z - mu) * rsv, g0.z, b0.z);
      float l3 = fmaf((f0.w - mu) * rsv, g0.w, b0.w);
      float l4 = fmaf((f1.x - mu) * rsv, g1v.x, b1v.x);
      float l5 = fmaf((f1.y - mu) * rsv, g1v.y, b1v.y);
      float l6 = fmaf((f1.z - mu) * rsv, g1v.z, b1v.z);
      float l7 = fmaf((f1.w - mu) * rsv, g1v.w, b1v.w);
      pe.x = pkt(f0.x, f0.y); pe.y = pkt(f0.z, f0.w);
      pe.z = pkt(f1.x, f1.y); pe.w = pkt(f1.z, f1.w);
      pl.x = pkt(l0, l1); pl.y = pkt(l2, l3);
      pl.z = pkt(l4, l5); pl.w = pkt(l6, l7);
    } else {
      pe = make_int4(0,0,0,0); pl = pe;
    }
    int sw = (r * 128 + cb * 16) ^ ((r & 7) << 4);
    *(int4*)(e16g + sw) = pe;
    *(int4*)((char*)LNE16 + sw) = pl;
  }
  __syncthreads();

  // ---- B-fragments straight from global w_ij (C2L folded) ----
  bf8 bw1[4][2], bw2[4][2];
#pragma unroll
  for (int n = 0; n < 4; ++n)
#pragma unroll
    for (int s = 0; s < 2; ++s) {
      const float* p1 = w_ij + (16 * n + c) * 192 + 8 * g + 32 * s;
      const float* p2 = p1 + 64;
      float4 a0 = *(const float4*)p1, a1 = *(const float4*)(p1 + 4);
      float4 q0 = *(const float4*)p2, q1 = *(const float4*)(p2 + 4);
      int4 pk;
      pk.x = pk2(a0.x * C2L, a0.y * C2L); pk.y = pk2(a0.z * C2L, a0.w * C2L);
      pk.z = pk2(a1.x * C2L, a1.y * C2L); pk.w = pk2(a1.z * C2L, a1.w * C2L);
      bw1[n][s] = *(bf8*)&pk;
      pk.x = pk2(q0.x * C2L, q0.y * C2L); pk.y = pk2(q0.z * C2L, q0.w * C2L);
      pk.z = pk2(q1.x * C2L, q1.y * C2L); pk.w = pk2(q1.z * C2L, q1.w * C2L);
      bw2[n][s] = *(bf8*)&pk;
    }

  // ---- PA/PB GEMM over m-tiles (wave wv owns m = wv, wv+4) ----
  for (int m = wv; m < 7; m += 4) {
    bf8 a[2];
#pragma unroll
    for (int s = 0; s < 2; ++s) {
      int r = 16 * m + c;
      a[s] = *(bf8*)((char*)LNE16 + ((r * 128 + 16 * g + 64 * s) ^ ((r & 7) << 4)));
    }
    f32x4 pa[4], pbk[4];
#pragma unroll
    for (int n = 0; n < 4; ++n) { pa[n] = (f32x4)0.f; pbk[n] = (f32x4)0.f; }
#pragma unroll
    for (int s = 0; s < 2; ++s)
#pragma unroll
      for (int n = 0; n < 4; ++n) {
        pa[n]  = __builtin_amdgcn_mfma_f32_16x16x32_bf16(a[s], bw1[n][s], pa[n], 0, 0, 0);
        pbk[n] = __builtin_amdgcn_mfma_f32_16x16x32_bf16(a[s], bw2[n][s], pbk[n], 0, 0, 0);
      }
#pragma unroll
    for (int reg = 0; reg < 4; ++reg) {
      int j = 16 * m + 4 * g + reg;
      uint2 v;
      v.x = (uint32_t)pk2(pa[0][reg], pa[1][reg]);
      v.y = (uint32_t)pk2(pa[2][reg], pa[3][reg]);
      *(uint2*)(pa16g + j * 128 + c * 8) = v;     // [j][x=c][n]
      if (j < NI) {
#pragma unroll
        for (int n = 0; n < 4; ++n)
          pb16[(b * NI + j) * 64 + 16 * n + c] = (ushort)f2bf(pbk[n][reg]);
      }
    }
  }
}

// K2: pair-wave decomposition. Block = 4 waves = 2 i's; wave (p=wv>>1, r=wv&1)
// owns i = 2*it+p, m-tiles m = r, r+2, ... (4/3 split). Barrier; r=0 softmax;
// barrier; PV split by j-range with LDS combine. Grid 3200.
__global__ __launch_bounds__(256, 2) void k2_main(
    const float* __restrict__ emb,
    const float* __restrict__ wsum,
    const float* __restrict__ bsum,
    const float* __restrict__ ws,
    float* __restrict__ out) {
  int bid = blockIdx.x;
  int b = bid & 63, it = bid >> 6;     // it = 0..49
  int tid = threadIdx.x;
  int wv = tid >> 6, lane = tid & 63, g = lane >> 4, c = lane & 15;
  int p = wv >> 1, r = wv & 1;
  int i = 2 * it + p;                  // 0..99

  __shared__ ushort E16[NIP * 64];   // 14336 B: bf16 e_j, swizzled
  __shared__ float z_s[2][NIP];      // per-i z then alpha
  __shared__ float part[2][128];     // PV partials [i-pair][r*64 + k]

  const char* e16g  = (const char*)ws + OFF_E16  * 4 + b * TILEB;
  const char* pa16g = (const char*)ws + OFF_PA16 * 4 + b * TILEB;
  const ushort* pb16 = (const ushort*)(ws + OFF_PB16);

  // stage E16 (linear copy; swizzle baked in)
  for (int u = tid; u < TILEB / 16; u += 256)
    ((int4*)E16)[u] = ((const int4*)e16g)[u];

  // ---- per-wave i-row fragments: aEi (all rows = e_i), aEisq, bw3 ----
  const float* ei = emb + (b * NI + i) * 64;
  float4 eif[4];
#pragma unroll
  for (int s = 0; s < 2; ++s) {
    eif[2*s]   = *(const float4*)(ei + 8 * g + 32 * s);
    eif[2*s+1] = *(const float4*)(ei + 8 * g + 32 * s + 4);
  }
  bf8 aEi[2], aEisq[2];
#pragma unroll
  for (int s = 0; s < 2; ++s) {
    float4 e0 = eif[2*s], e1 = eif[2*s+1];
    int4 pk;
    pk.x = pkt(e0.x, e0.y); pk.y = pkt(e0.z, e0.w);
    pk.z = pkt(e1.x, e1.y); pk.w = pkt(e1.z, e1.w);
    aEi[s] = *(bf8*)&pk;
    pk.x = pkt(e0.x*e0.x, e0.y*e0.y); pk.y = pkt(e0.z*e0.z, e0.w*e0.w);
    pk.z = pkt(e1.x*e1.x, e1.y*e1.y); pk.w = pkt(e1.z*e1.z, e1.w*e1.w);
    aEisq[s] = *(bf8*)&pk;
  }
  bf8 bw3[4][2];
  {
    const float* w3 = ws + OFF_W3GTT;
#pragma unroll
    for (int n = 0; n < 4; ++n) {
      int d = 16 * n + c;
#pragma unroll
      for (int s = 0; s < 2; ++s) {
        const float* wp = w3 + d * 64 + 8 * g + 32 * s;
        float4 w0 = *(const float4*)wp, w1v = *(const float4*)(wp + 4);
        float4 e0 = eif[2*s], e1 = eif[2*s+1];
        int4 pk;
        pk.x = pkt(w0.x * e0.x, w0.y * e0.y);
        pk.y = pkt(w0.z * e0.z, w0.w * e0.w);
        pk.z = pkt(w1v.x * e1.x, w1v.y * e1.y);
        pk.w = pkt(w1v.z * e1.z, w1v.w * e1.w);
        bw3[n][s] = *(bf8*)&pk;
      }
    }
  }

  // per-lane epilogue constants: d = 16n + 4g + reg
  float w3g_nr[4][4], cst2_nr[4][4], wsum_nr[4][4];
#pragma unroll
  for (int n = 0; n < 4; ++n) {
    int d0 = 16 * n + 4 * g;
    float4 wg  = *(const float4*)(ws + OFF_W3G + d0);
    float4 c0v = *(const float4*)(ws + OFF_C0 + d0);
    float4 wsv = *(const float4*)(wsum + d0);
    uint2 pbu = *(const uint2*)(pb16 + (b * NI + i) * 64 + d0);
    float pbf[4];
    pbf[0] = __uint_as_float(pbu.x << 16);
    pbf[1] = __uint_as_float(pbu.x & 0xffff0000u);
    pbf[2] = __uint_as_float(pbu.y << 16);
    pbf[3] = __uint_as_float(pbu.y & 0xffff0000u);
    w3g_nr[n][0] = wg.x;  w3g_nr[n][1] = wg.y;  w3g_nr[n][2] = wg.z;  w3g_nr[n][3] = wg.w;
    wsum_nr[n][0] = wsv.x; wsum_nr[n][1] = wsv.y; wsum_nr[n][2] = wsv.z; wsum_nr[n][3] = wsv.w;
    cst2_nr[n][0] = pbf[0] + c0v.x; cst2_nr[n][1] = pbf[1] + c0v.y;
    cst2_nr[n][2] = pbf[2] + c0v.z; cst2_nr[n][3] = pbf[3] + c0v.w;
  }
  float zbase = ws[OFF_WSUMS] + bsum[0];

  __syncthreads();   // E16 staged

  // ---- fused stats + pass Q over this wave's m-tiles (m = r, r+2, ...) ----
  for (int m = r; m < 7; m += 2) {
    int jrow = 16 * m + c;
    int4 paA = *(const int4*)(pa16g + jrow * 128 + 32 * g);
    int4 paB = *(const int4*)(pa16g + jrow * 128 + 32 * g + 16);
    bf8 a[2], ajs[2];
#pragma unroll
    for (int s = 0; s < 2; ++s) {
      int sw = (jrow * 128 + 16 * g + 64 * s) ^ ((jrow & 7) << 4);
      a[s] = *(const bf8*)((const char*)E16 + sw);
      ajs[s] = sq8t(a[s]);
    }
    f32x4 g1 = (f32x4)0.f, g2 = (f32x4)0.f, q3[4];
#pragma unroll
    for (int n = 0; n < 4; ++n) q3[n] = (f32x4)0.f;
#pragma unroll
    for (int s = 0; s < 2; ++s) {
      g1 = __builtin_amdgcn_mfma_f32_16x16x32_bf16(aEi[s],   a[s],   g1, 0, 0, 0);
      g2 = __builtin_amdgcn_mfma_f32_16x16x32_bf16(aEisq[s], ajs[s], g2, 0, 0, 0);
#pragma unroll
      for (int n = 0; n < 4; ++n)
        q3[n] = __builtin_amdgcn_mfma_f32_16x16x32_bf16(bw3[n][s], a[s], q3[n], 0, 0, 0);
    }
    // all C rows equal -> lane (c,g) reads its j=16m+c stat at [0]
    float mu  = g1[0] * (1.f / 64.f);
    float v2  = g2[0] * (1.f / 64.f);
    float var = v2 - mu * mu;
    float rsv = rsqrtf(var + LN_EPS);
    float rs2c  = C2L * rsv;
    float mrs2c = -C2L * mu * rsv;

    uint32_t pw[4][2] = {{(uint32_t)paA.x, (uint32_t)paA.y},
                         {(uint32_t)paA.z, (uint32_t)paA.w},
                         {(uint32_t)paB.x, (uint32_t)paB.y},
                         {(uint32_t)paB.z, (uint32_t)paB.w}};
    float zacc0 = 0.f, zacc1 = 0.f;
#pragma unroll
    for (int reg = 0; reg < 4; ++reg) {
      float paf[4];
      paf[0] = __uint_as_float(pw[reg][0] << 16);
      paf[1] = __uint_as_float(pw[reg][0] & 0xffff0000u);
      paf[2] = __uint_as_float(pw[reg][1] << 16);
      paf[3] = __uint_as_float(pw[reg][1] & 0xffff0000u);
#pragma unroll
      for (int n = 0; n < 4; ++n) {
        float X = fmaf(rs2c, q3[n][reg],
                   fmaf(mrs2c, w3g_nr[n][reg], paf[n] + cst2_nr[n][reg]));
        float ex = fast_exp2(X);                      // e^{2x}
        float rr = __builtin_amdgcn_rcpf(ex + 1.f);   // tanh = 1 - 2*rr
        if (n & 1) zacc1 = fmaf(wsum_nr[n][reg], rr, zacc1);
        else       zacc0 = fmaf(wsum_nr[n][reg], rr, zacc0);
      }
    }
    float zacc = zacc0 + zacc1;
    zacc += __shfl_xor(zacc, 16, 64);
    zacc += __shfl_xor(zacc, 32, 64);
    if (g == 0)
      z_s[p][jrow] = fmaf(-2.f, zacc, zbase);
  }
  __syncthreads();   // all z for both i's ready

  // ---- softmax (r==0 wave per pair) ----
  if (r == 0) {
    int j0 = lane, j1 = lane + 64;
    bool v0 = (j0 != i);
    bool v1 = (j1 < NI) && (j1 != i);
    float z0 = z_s[p][j0];
    float z1 = (j1 < NIP) ? z_s[p][j1] : 0.f;
    z0 = v0 ? z0 : -__builtin_inff();
    z1 = v1 ? z1 : -__builtin_inff();
    float mx = fmaxf(z0, z1);
#pragma unroll
    for (int off = 32; off > 0; off >>= 1)
      mx = fmaxf(mx, __shfl_xor(mx, off, 64));
    float e0 = v0 ? __expf(z0 - mx) : 0.f;
    float e1 = v1 ? __expf(z1 - mx) : 0.f;
    float ss = e0 + e1;
#pragma unroll
    for (int off = 32; off > 0; off >>= 1)
      ss += __shfl_xor(ss, off, 64);
    float inv = __builtin_amdgcn_rcpf(ss);
    z_s[p][j0] = e0 * inv;
    if (j1 < NIP) z_s[p][j1] = e1 * inv;
  }
  __syncthreads();   // alphas ready

  // ---- PV: wave r handles j in [r*56, r*56+56); 28 iters per lane-half ----
  {
    int kp = lane & 31, half = lane >> 5;
    int jb = r * 56 + half * 28;
    float s0 = 0.f, s1 = 0.f, s0b = 0.f, s1b = 0.f;
#pragma unroll
    for (int t = 0; t < 28; t += 2) {
      int j = jb + t, j2 = jb + t + 1;
      float2 al = *(const float2*)&z_s[p][j];
      int sw  = (j  * 128 + kp * 4) ^ ((j  & 7) << 4);
      int sw2 = (j2 * 128 + kp * 4) ^ ((j2 & 7) << 4);
      uint32_t e0u = *(const uint32_t*)((const char*)E16 + sw);
      uint32_t e1u = *(const uint32_t*)((const char*)E16 + sw2);
      s0  = fmaf(al.x, __uint_as_float(e0u << 16), s0);
      s1  = fmaf(al.x, __uint_as_float(e0u & 0xffff0000u), s1);
      s0b = fmaf(al.y, __uint_as_float(e1u << 16), s0b);
      s1b = fmaf(al.y, __uint_as_float(e1u & 0xffff0000u), s1b);
    }
    float sf0 = s0 + s0b, sf1 = s1 + s1b;
    sf0 += __shfl_xor(sf0, 32, 64);
    sf1 += __shfl_xor(sf1, 32, 64);
    if (half == 0) {
      part[p][r * 64 + 2 * kp]     = sf0;
      part[p][r * 64 + 2 * kp + 1] = sf1;
    }
  }
  __syncthreads();   // partials ready

  // ---- final combine + epilogue (r==0 wave, lane = k) ----
  if (r == 0) {
    float v = part[p][lane] + part[p][64 + lane];
    float eiv = ei[lane];
    float ctx = fmaf(eiv, v, eiv * eiv);
    ctx = (ctx >= 0.f) ? ctx : 0.01f * ctx;
    out[(b * NI + i) * 64 + lane] = ctx;
  }
}

extern "C" void kernel_launch(void* const* d_in, const int* in_sizes, int n_in,
                              void* d_out, int out_size, void* d_ws, size_t ws_size,
                              hipStream_t stream) {
  const float* emb  = (const float*)d_in[0];
  const float* g    = (const float*)d_in[1];
  const float* bln  = (const float*)d_in[2];
  const float* w_ij = (const float*)d_in[3];
  const float* bij  = (const float*)d_in[4];
  const float* wsum = (const float*)d_in[5];
  const float* bsum = (const float*)d_in[6];
  float* ws  = (float*)d_ws;
  float* out = (float*)d_out;

  hipLaunchKernelGGL(k1_batch, dim3(BSZ), dim3(256), 0, stream,
                     emb, g, bln, w_ij, bij, wsum, ws);
  hipLaunchKernelGGL(k2_main, dim3(BSZ * 50), dim3(256), 0, stream,
                     emb, wsum, bsum, ws, out);
}

// Round 19
// 53.323 us; speedup vs baseline: 1.2120x; 1.2120x over previous
//
#include <hip/hip_runtime.h>
#include <math.h>

#define D 64
#define NI 100
#define BSZ 64
#define LN_EPS 1e-5f
#define NIP 112            // padded j rows (7 tiles of 16)
#define IT 4               // i's per block
#define NT2 25             // i-tiles per batch
#define C2L 2.8853900817779268f   // 2*log2(e)
#define TILEB 14336        // bytes per per-batch bf16 tile (NIP*64*2)

// ws layout (float indices) — proven 3.605 MB envelope:
#define OFF_W3GTT 0        // f32 [d][k] = w3[d,k]*g[k]            (4096)
#define OFF_W1B   4096     // (reserved, unused)
#define OFF_W2B   6144     // (reserved, unused)
#define OFF_W3G   8192     // f32 [64] sum_k w3[d,k]*g[k]
#define OFF_C0    8256     // f32 [64] C2L*(bij[d] + sum_k w3[d,k]*bln[k])
#define OFF_WSUMS 8320     // f32 [1] sum(wsum)
#define OFF_PB16  8448     // bf16 [6400*64] = C2L * LN(e_t).w2    (204800 f32 slots)
#define OFF_E16   213248   // 64 x TILEB: bf16 e, swizzled         (229376 floats)
#define OFF_E2    442624   // (reserved, unused — keeps envelope identical)
#define OFF_PA16  672000   // 64 x TILEB: bf16 PA [j][x][n]        (229376 floats)
// end: 901376 floats = 3.605 MB (proven)

typedef __attribute__((ext_vector_type(8))) short bf8;
typedef __attribute__((ext_vector_type(4))) float f32x4;

// raw v_exp_f32 (no OCML fixup; |arg| << 126 here)
__device__ inline float fast_exp2(float x) {
#if __has_builtin(__builtin_amdgcn_exp2f)
  return __builtin_amdgcn_exp2f(x);
#else
  float r; asm("v_exp_f32 %0, %1" : "=v"(r) : "v"(x)); return r;
#endif
}

// rounding f32->bf16
__device__ inline uint32_t f2bf(float x) {
  uint32_t u = __float_as_uint(x);
  return (u + 0x7fffu + ((u >> 16) & 1u)) >> 16;
}
__device__ inline int pk2(float a, float b) { return (int)(f2bf(a) | (f2bf(b) << 16)); }
// truncating pack (3 ops)
__device__ inline int pkt(float a, float b) {
  return (int)((__float_as_uint(a) >> 16) | (__float_as_uint(b) & 0xffff0000u));
}
// square a bf16x8 fragment, truncating round
__device__ inline bf8 sq8t(bf8 a) {
  bf8 r;
#pragma unroll
  for (int t = 0; t < 8; ++t) {
    float v = __uint_as_float(((uint32_t)(unsigned short)a[t]) << 16);
    r[t] = (short)(__float_as_uint(v * v) >> 16);
  }
  return r;
}

// K1: one block per batch b. Also computes the k2 weight tables (distributed:
// block b owns W3GTT row b, W3G[b], C0[b]; block 0 wave 1 does WSUMS).
// Emits E16 (swizzled bf16), PA16 = C2L*LNE.w1 (bf16 [j][x][n]),
// PB16 = C2L*LNE.w2 (bf16 [t][d]).
__global__ __launch_bounds__(256) void k1_batch(
    const float* __restrict__ emb,
    const float* __restrict__ gg,
    const float* __restrict__ bb,
    const float* __restrict__ w_ij,
    const float* __restrict__ bij,
    const float* __restrict__ wsum,
    float* __restrict__ ws) {
  int b = blockIdx.x;
  int tid = threadIdx.x;
  int wv = tid >> 6, lane = tid & 63, g = lane >> 4, c = lane & 15;

  __shared__ ushort LNE16[NIP * 64];   // 14336 B, swizzled
  char* e16g  = (char*)ws + OFF_E16  * 4 + b * TILEB;
  char* pa16g = (char*)ws + OFF_PA16 * 4 + b * TILEB;
  ushort* pb16 = (ushort*)(ws + OFF_PB16);
  const float* eb = emb + b * NI * D;

  // ---- table slice (read only by k2; k1 never reads these) ----
  if (wv == 0) {
    float w  = w_ij[b * 192 + 128 + lane];   // w3[b][k=lane]
    float gk = gg[lane];
    ws[OFF_W3GTT + b * 64 + lane] = w * gk;
    float wg = w * gk, wb = w * bb[lane];
#pragma unroll
    for (int off = 32; off > 0; off >>= 1) {
      wg += __shfl_xor(wg, off, 64);
      wb += __shfl_xor(wb, off, 64);
    }
    if (lane == 0) {
      ws[OFF_W3G + b] = wg;
      ws[OFF_C0 + b]  = C2L * (bij[b] + wb);
    }
  } else if (wv == 1 && b == 0) {
    float v = wsum[lane];
#pragma unroll
    for (int off = 32; off > 0; off >>= 1)
      v += __shfl_xor(v, off, 64);
    if (lane == 0) ws[OFF_WSUMS] = v;
  }

  // ---- stage: e -> E16(global), LN(e) -> LNE16(LDS) ----
  for (int u = tid; u < NIP * 8; u += 256) {
    int r = u >> 3, cb = u & 7, kk = cb * 8;
    int4 pe, pl;
    if (r < NI) {
      const float* sp = eb + r * 64 + kk;
      float4 f0 = *(const float4*)sp, f1 = *(const float4*)(sp + 4);
      float s  = f0.x + f0.y + f0.z + f0.w + f1.x + f1.y + f1.z + f1.w;
      float s2 = f0.x*f0.x + f0.y*f0.y + f0.z*f0.z + f0.w*f0.w
               + f1.x*f1.x + f1.y*f1.y + f1.z*f1.z + f1.w*f1.w;
#pragma unroll
      for (int off = 1; off < 8; off <<= 1) {
        s  += __shfl_xor(s, off, 64);
        s2 += __shfl_xor(s2, off, 64);
      }
      float mu  = s * (1.f / 64.f);
      float var = s2 * (1.f / 64.f) - mu * mu;
      float rsv = rsqrtf(var + LN_EPS);
      float4 g0 = *(const float4*)(gg + kk), g1v = *(const float4*)(gg + kk + 4);
      float4 b0 = *(const float4*)(bb + kk), b1v = *(const float4*)(bb + kk + 4);
      float l0 = fmaf((f0.x - mu) * rsv, g0.x, b0.x);
      float l1 = fmaf((f0.y - mu) * rsv, g0.y, b0.y);
      float l2 = fmaf((f0.z - mu) * rsv, g0.z, b0.z);
      float l3 = fmaf((f0.w - mu) * rsv, g0.w, b0.w);
      float l4 = fmaf((f1.x - mu) * rsv, g1v.x, b1v.x);
      float l5 = fmaf((f1.y - mu) * rsv, g1v.y, b1v.y);
      float l6 = fmaf((f1.z - mu) * rsv, g1v.z, b1v.z);
      float l7 = fmaf((f1.w - mu) * rsv, g1v.w, b1v.w);
      pe.x = pkt(f0.x, f0.y); pe.y = pkt(f0.z, f0.w);
      pe.z = pkt(f1.x, f1.y); pe.w = pkt(f1.z, f1.w);
      pl.x = pkt(l0, l1); pl.y = pkt(l2, l3);
      pl.z = pkt(l4, l5); pl.w = pkt(l6, l7);
    } else {
      pe = make_int4(0,0,0,0); pl = pe;
    }
    int sw = (r * 128 + cb * 16) ^ ((r & 7) << 4);
    *(int4*)(e16g + sw) = pe;
    *(int4*)((char*)LNE16 + sw) = pl;
  }
  __syncthreads();

  // ---- B-fragments straight from global w_ij (C2L folded) ----
  bf8 bw1[4][2], bw2[4][2];
#pragma unroll
  for (int n = 0; n < 4; ++n)
#pragma unroll
    for (int s = 0; s < 2; ++s) {
      const float* p1 = w_ij + (16 * n + c) * 192 + 8 * g + 32 * s;  // w1 cols
      const float* p2 = p1 + 64;                                      // w2 cols
      float4 a0 = *(const float4*)p1, a1 = *(const float4*)(p1 + 4);
      float4 q0 = *(const float4*)p2, q1 = *(const float4*)(p2 + 4);
      int4 pk;
      pk.x = pk2(a0.x * C2L, a0.y * C2L); pk.y = pk2(a0.z * C2L, a0.w * C2L);
      pk.z = pk2(a1.x * C2L, a1.y * C2L); pk.w = pk2(a1.z * C2L, a1.w * C2L);
      bw1[n][s] = *(bf8*)&pk;
      pk.x = pk2(q0.x * C2L, q0.y * C2L); pk.y = pk2(q0.z * C2L, q0.w * C2L);
      pk.z = pk2(q1.x * C2L, q1.y * C2L); pk.w = pk2(q1.z * C2L, q1.w * C2L);
      bw2[n][s] = *(bf8*)&pk;
    }

  // ---- PA/PB GEMM over m-tiles (wave wv owns m = wv, wv+4) ----
  for (int m = wv; m < 7; m += 4) {
    bf8 a[2];
#pragma unroll
    for (int s = 0; s < 2; ++s) {
      int r = 16 * m + c;
      a[s] = *(bf8*)((char*)LNE16 + ((r * 128 + 16 * g + 64 * s) ^ ((r & 7) << 4)));
    }
    f32x4 pa[4], pbk[4];
#pragma unroll
    for (int n = 0; n < 4; ++n) { pa[n] = (f32x4)0.f; pbk[n] = (f32x4)0.f; }
#pragma unroll
    for (int s = 0; s < 2; ++s)
#pragma unroll
      for (int n = 0; n < 4; ++n) {
        pa[n]  = __builtin_amdgcn_mfma_f32_16x16x32_bf16(a[s], bw1[n][s], pa[n], 0, 0, 0);
        pbk[n] = __builtin_amdgcn_mfma_f32_16x16x32_bf16(a[s], bw2[n][s], pbk[n], 0, 0, 0);
      }
#pragma unroll
    for (int reg = 0; reg < 4; ++reg) {
      int j = 16 * m + 4 * g + reg;
      uint2 v;
      v.x = (uint32_t)pk2(pa[0][reg], pa[1][reg]);
      v.y = (uint32_t)pk2(pa[2][reg], pa[3][reg]);
      *(uint2*)(pa16g + j * 128 + c * 8) = v;     // [j][x=c][n], no swizzle
      if (j < NI) {
#pragma unroll
        for (int n = 0; n < 4; ++n)
          pb16[(b * NI + j) * 64 + 16 * n + c] = (ushort)f2bf(pbk[n][reg]);
      }
    }
  }
}

// K2: one block per (b, 4-i tile); wave wv owns i = i0+wv end-to-end.
// XCD swizzle: b = bid & 63. Swapped-operand pass Q: Q[d][j], d on regs, j on lanes.
// Gram squares via in-register sq8t.
__global__ __launch_bounds__(256, 3) void k2_main(
    const float* __restrict__ emb,
    const float* __restrict__ wsum,
    const float* __restrict__ bsum,
    const float* __restrict__ ws,
    float* __restrict__ out) {
  int bid = blockIdx.x;
  int b = bid & 63, itile = bid >> 6;
  int i0 = itile * IT;
  int tid = threadIdx.x;
  int wv = tid >> 6, lane = tid & 63, g = lane >> 4, c = lane & 15;
  int i = i0 + wv;

  __shared__ ushort E16[NIP * 64];   // 14336 B: bf16 e_j, swizzled
  __shared__ float rs2_s[IT][NIP];   // C2L*rs
  __shared__ float mrs2_s[IT][NIP];  // -C2L*mu*rs
  __shared__ float z_s[IT][NIP];     // z then alpha

  const char* e16g  = (const char*)ws + OFF_E16  * 4 + b * TILEB;
  const char* pa16g = (const char*)ws + OFF_PA16 * 4 + b * TILEB;
  const ushort* pb16 = (const ushort*)(ws + OFF_PB16);

  // stage E16 (linear copy; swizzle baked in)
  for (int u = tid; u < TILEB / 16; u += 256)
    ((int4*)E16)[u] = ((const int4*)e16g)[u];
  __syncthreads();

  // ---- Gram stats (squares in-register via sq8t) ----
  {
    bf8 aI[2], aIsq[2];
#pragma unroll
    for (int s = 0; s < 2; ++s) {
      int r = i0 + c;
      int sw = (r * 128 + 16 * g + 64 * s) ^ ((r & 7) << 4);
      aI[s]   = *(bf8*)((char*)E16 + sw);
      aIsq[s] = sq8t(aI[s]);
    }
    for (int jt = wv; jt < 7; jt += 4) {
      f32x4 g1 = (f32x4)0.f, g2 = (f32x4)0.f;
#pragma unroll
      for (int s = 0; s < 2; ++s) {
        int r = 16 * jt + c;
        int sw = (r * 128 + 16 * g + 64 * s) ^ ((r & 7) << 4);
        bf8 aj  = *(bf8*)((char*)E16 + sw);
        bf8 ajs = sq8t(aj);
        g1 = __builtin_amdgcn_mfma_f32_16x16x32_bf16(aI[s],   aj,  g1, 0, 0, 0);
        g2 = __builtin_amdgcn_mfma_f32_16x16x32_bf16(aIsq[s], ajs, g2, 0, 0, 0);
      }
      if (g == 0) {
#pragma unroll
        for (int reg = 0; reg < 4; ++reg) {
          float mu  = g1[reg] * (1.f / 64.f);
          float v2  = g2[reg] * (1.f / 64.f);
          float var = v2 - mu * mu;
          float rsv = rsqrtf(var + LN_EPS);
          rs2_s[reg][16 * jt + c]  = C2L * rsv;
          mrs2_s[reg][16 * jt + c] = -C2L * mu * rsv;
        }
      }
    }
  }

  // ---- bw3 fragments (e_i o w3g), A operand (rows = d) ----
  bf8 bw3[4][2];
  {
    const float* ei = emb + (b * NI + i) * 64;
    float4 eif[4];
#pragma unroll
    for (int s = 0; s < 2; ++s) {
      eif[2*s]   = *(const float4*)(ei + 8 * g + 32 * s);
      eif[2*s+1] = *(const float4*)(ei + 8 * g + 32 * s + 4);
    }
    const float* w3 = ws + OFF_W3GTT;
#pragma unroll
    for (int n = 0; n < 4; ++n) {
      int d = 16 * n + c;
#pragma unroll
      for (int s = 0; s < 2; ++s) {
        const float* wp = w3 + d * 64 + 8 * g + 32 * s;
        float4 w0 = *(const float4*)wp, w1v = *(const float4*)(wp + 4);
        float4 e0 = eif[2*s], e1 = eif[2*s+1];
        int4 pk;
        pk.x = pkt(w0.x * e0.x, w0.y * e0.y);
        pk.y = pkt(w0.z * e0.z, w0.w * e0.w);
        pk.z = pkt(w1v.x * e1.x, w1v.y * e1.y);
        pk.w = pkt(w1v.z * e1.z, w1v.w * e1.w);
        bw3[n][s] = *(bf8*)&pk;
      }
    }
  }

  // per-lane epilogue constants: d = 16n + 4g + reg
  float w3g_nr[4][4], cst2_nr[4][4], wsum_nr[4][4];
#pragma unroll
  for (int n = 0; n < 4; ++n) {
    int d0 = 16 * n + 4 * g;
    float4 wg  = *(const float4*)(ws + OFF_W3G + d0);
    float4 c0v = *(const float4*)(ws + OFF_C0 + d0);
    float4 wsv = *(const float4*)(wsum + d0);
    uint2 pbu = *(const uint2*)(pb16 + (b * NI + i) * 64 + d0);
    float pbf[4];
    pbf[0] = __uint_as_float(pbu.x << 16);
    pbf[1] = __uint_as_float(pbu.x & 0xffff0000u);
    pbf[2] = __uint_as_float(pbu.y << 16);
    pbf[3] = __uint_as_float(pbu.y & 0xffff0000u);
    w3g_nr[n][0] = wg.x;  w3g_nr[n][1] = wg.y;  w3g_nr[n][2] = wg.z;  w3g_nr[n][3] = wg.w;
    wsum_nr[n][0] = wsv.x; wsum_nr[n][1] = wsv.y; wsum_nr[n][2] = wsv.z; wsum_nr[n][3] = wsv.w;
    cst2_nr[n][0] = pbf[0] + c0v.x; cst2_nr[n][1] = pbf[1] + c0v.y;
    cst2_nr[n][2] = pbf[2] + c0v.z; cst2_nr[n][3] = pbf[3] + c0v.w;
  }
  float zbase = ws[OFF_WSUMS] + bsum[0];

  __syncthreads();   // rs2/mrs2 ready (cross-wave)

  // ---- pass Q (swapped): q3[n][reg] = Q[d=16n+4g+reg][j=16m+c] ----
  for (int m = 0; m < 7; ++m) {
    int jrow = 16 * m + c;
    int4 pa0 = *(const int4*)(pa16g + jrow * 128 + 32 * g);
    int4 pa1 = *(const int4*)(pa16g + jrow * 128 + 32 * g + 16);
    f32x4 q3[4];
#pragma unroll
    for (int n = 0; n < 4; ++n) q3[n] = (f32x4)0.f;
#pragma unroll
    for (int s = 0; s < 2; ++s) {
      int sw = (jrow * 128 + 16 * g + 64 * s) ^ ((jrow & 7) << 4);
      bf8 a = *(bf8*)((char*)E16 + sw);
#pragma unroll
      for (int n = 0; n < 4; ++n)
        q3[n] = __builtin_amdgcn_mfma_f32_16x16x32_bf16(bw3[n][s], a, q3[n], 0, 0, 0);
    }
    float rs2c  = rs2_s[wv][jrow];
    float mrs2c = mrs2_s[wv][jrow];
    uint32_t pw[4][2] = {{(uint32_t)pa0.x, (uint32_t)pa0.y},
                         {(uint32_t)pa0.z, (uint32_t)pa0.w},
                         {(uint32_t)pa1.x, (uint32_t)pa1.y},
                         {(uint32_t)pa1.z, (uint32_t)pa1.w}};
    float zacc0 = 0.f, zacc1 = 0.f;
#pragma unroll
    for (int reg = 0; reg < 4; ++reg) {
      float paf[4];
      paf[0] = __uint_as_float(pw[reg][0] << 16);
      paf[1] = __uint_as_float(pw[reg][0] & 0xffff0000u);
      paf[2] = __uint_as_float(pw[reg][1] << 16);
      paf[3] = __uint_as_float(pw[reg][1] & 0xffff0000u);
#pragma unroll
      for (int n = 0; n < 4; ++n) {
        float X = fmaf(rs2c, q3[n][reg],
                   fmaf(mrs2c, w3g_nr[n][reg], paf[n] + cst2_nr[n][reg]));
        float ex = fast_exp2(X);                      // e^{2x}
        float rr = __builtin_amdgcn_rcpf(ex + 1.f);   // tanh = 1 - 2*rr
        if (n & 1) zacc1 = fmaf(wsum_nr[n][reg], rr, zacc1);
        else       zacc0 = fmaf(wsum_nr[n][reg], rr, zacc0);
      }
    }
    float zacc = zacc0 + zacc1;
    zacc += __shfl_xor(zacc, 16, 64);
    zacc += __shfl_xor(zacc, 32, 64);
    if (g == 0)
      z_s[wv][jrow] = fmaf(-2.f, zacc, zbase);
  }

  // ---- softmax (per wave, own row) ----
  {
    int j0 = lane, j1 = lane + 64;
    bool v0 = (j0 != i);
    bool v1 = (j1 < NI) && (j1 != i);
    float z0 = z_s[wv][j0];
    float z1 = (j1 < NIP) ? z_s[wv][j1] : 0.f;
    z0 = v0 ? z0 : -__builtin_inff();
    z1 = v1 ? z1 : -__builtin_inff();
    float mx = fmaxf(z0, z1);
#pragma unroll
    for (int off = 32; off > 0; off >>= 1)
      mx = fmaxf(mx, __shfl_xor(mx, off, 64));
    float e0 = v0 ? __expf(z0 - mx) : 0.f;
    float e1 = v1 ? __expf(z1 - mx) : 0.f;
    float ss = e0 + e1;
#pragma unroll
    for (int off = 32; off > 0; off >>= 1)
      ss += __shfl_xor(ss, off, 64);
    float inv = __builtin_amdgcn_rcpf(ss);
    z_s[wv][j0] = e0 * inv;
    if (j1 < NIP) z_s[wv][j1] = e1 * inv;
  }

  // ---- PV: halves of 56 j's, static-XOR 8-unroll, float2 alpha reads ----
  {
    int kp = lane & 31, half = lane >> 5;
    int jb = half * 56;                 // z_s[100..111]=0, E16 rows 100..111 = 0
    float s0 = 0.f, s1 = 0.f, s0b = 0.f, s1b = 0.f;
#pragma unroll
    for (int t8 = 0; t8 < 56; t8 += 8) {
      int j0 = jb + t8;                 // multiple of 8
#pragma unroll
      for (int u = 0; u < 8; u += 2) {
        int j = j0 + u, j2 = j0 + u + 1;
        float2 al = *(const float2*)&z_s[wv][j];
        int sw  = (j  * 128 + kp * 4) ^ ((u & 7) << 4);          // XOR compile-time
        int sw2 = (j2 * 128 + kp * 4) ^ (((u + 1) & 7) << 4);
        uint32_t e0u = *(const uint32_t*)((const char*)E16 + sw);
        uint32_t e1u = *(const uint32_t*)((const char*)E16 + sw2);
        s0  = fmaf(al.x, __uint_as_float(e0u << 16), s0);
        s1  = fmaf(al.x, __uint_as_float(e0u & 0xffff0000u), s1);
        s0b = fmaf(al.y, __uint_as_float(e1u << 16), s0b);
        s1b = fmaf(al.y, __uint_as_float(e1u & 0xffff0000u), s1b);
      }
    }
    float sf0 = s0 + s0b, sf1 = s1 + s1b;
    sf0 += __shfl_xor(sf0, 32, 64);
    sf1 += __shfl_xor(sf1, 32, 64);
    if (half == 0) {
      const float* ei = emb + (b * NI + i) * 64;
      float e0 = ei[2 * kp], e1 = ei[2 * kp + 1];
      float c0 = fmaf(e0, sf0, e0 * e0);
      float c1 = fmaf(e1, sf1, e1 * e1);
      c0 = (c0 >= 0.f) ? c0 : 0.01f * c0;
      c1 = (c1 >= 0.f) ? c1 : 0.01f * c1;
      float2 o; o.x = c0; o.y = c1;
      *(float2*)(out + (b * NI + i) * 64 + 2 * kp) = o;
    }
  }
}

extern "C" void kernel_launch(void* const* d_in, const int* in_sizes, int n_in,
                              void* d_out, int out_size, void* d_ws, size_t ws_size,
                              hipStream_t stream) {
  const float* emb  = (const float*)d_in[0];
  const float* g    = (const float*)d_in[1];
  const float* bln  = (const float*)d_in[2];
  const float* w_ij = (const float*)d_in[3];
  const float* bij  = (const float*)d_in[4];
  const float* wsum = (const float*)d_in[5];
  const float* bsum = (const float*)d_in[6];
  float* ws  = (float*)d_ws;
  float* out = (float*)d_out;

  hipLaunchKernelGGL(k1_batch, dim3(BSZ), dim3(256), 0, stream,
                     emb, g, bln, w_ij, bij, wsum, ws);
  hipLaunchKernelGGL(k2_main, dim3(BSZ * NT2), dim3(256), 0, stream,
                     emb, wsum, bsum, ws, out);
}

// Round 20
// 50.745 us; speedup vs baseline: 1.2736x; 1.0508x over previous
//
#include <hip/hip_runtime.h>
#include <math.h>

#define D 64
#define NI 100
#define BSZ 64
#define LN_EPS 1e-5f
#define NIP 112            // padded j rows (7 tiles of 16)
#define IT 4               // i's per block
#define NT2 25             // i-tiles per batch
#define C2L 2.8853900817779268f   // 2*log2(e)
#define TILEB 14336        // bytes per per-batch bf16 tile (NIP*64*2)

// ws layout (float indices) — proven 3.605 MB envelope:
#define OFF_W3GTT 0        // f32 [d][k] = w3[d,k]*g[k]            (4096)
#define OFF_W3G   8192     // f32 [64] sum_k w3[d,k]*g[k]
#define OFF_C0    8256     // f32 [64] C2L*(bij[d] + sum_k w3[d,k]*bln[k])
#define OFF_WSUMS 8320     // f32 [1] sum(wsum)
#define OFF_PB16  8448     // bf16 [6400*64] = C2L * LN(e_t).w2    (204800 f32 slots)
#define OFF_E16   213248   // 64 x TILEB: bf16 e, swizzled         (229376 floats)
#define OFF_E2    442624   // (reserved, unused — keeps envelope identical)
#define OFF_PA16  672000   // 64 x TILEB: bf16 PA [j][x][n]        (229376 floats)
// end: 901376 floats = 3.605 MB (proven)

typedef __attribute__((ext_vector_type(8))) short bf8;
typedef __attribute__((ext_vector_type(4))) float f32x4;

// raw v_exp_f32 (no OCML fixup; |arg| << 126 here)
__device__ inline float fast_exp2(float x) {
#if __has_builtin(__builtin_amdgcn_exp2f)
  return __builtin_amdgcn_exp2f(x);
#else
  float r; asm("v_exp_f32 %0, %1" : "=v"(r) : "v"(x)); return r;
#endif
}

// rounding f32->bf16
__device__ inline uint32_t f2bf(float x) {
  uint32_t u = __float_as_uint(x);
  return (u + 0x7fffu + ((u >> 16) & 1u)) >> 16;
}
__device__ inline int pk2(float a, float b) { return (int)(f2bf(a) | (f2bf(b) << 16)); }
// truncating pack (3 ops)
__device__ inline int pkt(float a, float b) {
  return (int)((__float_as_uint(a) >> 16) | (__float_as_uint(b) & 0xffff0000u));
}
// square a bf16x8 fragment, truncating round
__device__ inline bf8 sq8t(bf8 a) {
  bf8 r;
#pragma unroll
  for (int t = 0; t < 8; ++t) {
    float v = __uint_as_float(((uint32_t)(unsigned short)a[t]) << 16);
    r[t] = (short)(__float_as_uint(v * v) >> 16);
  }
  return r;
}

// K1: tile-parallel — grid 448 = (batch b, m-tile m); ONE wave per block.
// Each block LNs its 16 rows, writes its E16 slice, computes its PA/PB m-tile.
// Tables ride on (m==0) blocks; WSUMS on (b==0, m==1). Math identical to R19 k1.
__global__ __launch_bounds__(64) void k1_tile(
    const float* __restrict__ emb,
    const float* __restrict__ gg,
    const float* __restrict__ bb,
    const float* __restrict__ w_ij,
    const float* __restrict__ bij,
    const float* __restrict__ wsum,
    float* __restrict__ ws) {
  int bid = blockIdx.x;
  int b = bid / 7, m = bid - b * 7;
  int lane = threadIdx.x;          // 0..63
  int g = lane >> 4, c = lane & 15;

  __shared__ ushort LNE16[16 * 64];   // 2 KB, local 16-row tile, swizzled by rloc
  char* e16g  = (char*)ws + OFF_E16  * 4 + b * TILEB;
  char* pa16g = (char*)ws + OFF_PA16 * 4 + b * TILEB;
  ushort* pb16 = (ushort*)(ws + OFF_PB16);
  const float* eb = emb + b * NI * D;

  // ---- table slices ----
  if (m == 0) {
    float w  = w_ij[b * 192 + 128 + lane];   // w3[b][k=lane]
    float gk = gg[lane];
    ws[OFF_W3GTT + b * 64 + lane] = w * gk;
    float wg = w * gk, wb = w * bb[lane];
#pragma unroll
    for (int off = 32; off > 0; off >>= 1) {
      wg += __shfl_xor(wg, off, 64);
      wb += __shfl_xor(wb, off, 64);
    }
    if (lane == 0) {
      ws[OFF_W3G + b] = wg;
      ws[OFF_C0 + b]  = C2L * (bij[b] + wb);
    }
  } else if (m == 1 && b == 0) {
    float v = wsum[lane];
#pragma unroll
    for (int off = 32; off > 0; off >>= 1)
      v += __shfl_xor(v, off, 64);
    if (lane == 0) ws[OFF_WSUMS] = v;
  }

  // ---- LN + stage this tile's 16 rows (8 lanes/row, 2 passes) ----
#pragma unroll
  for (int pass = 0; pass < 2; ++pass) {
    int rloc = (lane >> 3) + 8 * pass;   // 0..15
    int cb = lane & 7, kk = cb * 8;
    int r = 16 * m + rloc;
    int4 pe, pl;
    if (r < NI) {
      const float* sp = eb + r * 64 + kk;
      float4 f0 = *(const float4*)sp, f1 = *(const float4*)(sp + 4);
      float s  = f0.x + f0.y + f0.z + f0.w + f1.x + f1.y + f1.z + f1.w;
      float s2 = f0.x*f0.x + f0.y*f0.y + f0.z*f0.z + f0.w*f0.w
               + f1.x*f1.x + f1.y*f1.y + f1.z*f1.z + f1.w*f1.w;
#pragma unroll
      for (int off = 1; off < 8; off <<= 1) {
        s  += __shfl_xor(s, off, 64);
        s2 += __shfl_xor(s2, off, 64);
      }
      float mu  = s * (1.f / 64.f);
      float var = s2 * (1.f / 64.f) - mu * mu;
      float rsv = rsqrtf(var + LN_EPS);
      float4 g0 = *(const float4*)(gg + kk), g1v = *(const float4*)(gg + kk + 4);
      float4 b0 = *(const float4*)(bb + kk), b1v = *(const float4*)(bb + kk + 4);
      float l0 = fmaf((f0.x - mu) * rsv, g0.x, b0.x);
      float l1 = fmaf((f0.y - mu) * rsv, g0.y, b0.y);
      float l2 = fmaf((f0.z - mu) * rsv, g0.z, b0.z);
      float l3 = fmaf((f0.w - mu) * rsv, g0.w, b0.w);
      float l4 = fmaf((f1.x - mu) * rsv, g1v.x, b1v.x);
      float l5 = fmaf((f1.y - mu) * rsv, g1v.y, b1v.y);
      float l6 = fmaf((f1.z - mu) * rsv, g1v.z, b1v.z);
      float l7 = fmaf((f1.w - mu) * rsv, g1v.w, b1v.w);
      pe.x = pkt(f0.x, f0.y); pe.y = pkt(f0.z, f0.w);
      pe.z = pkt(f1.x, f1.y); pe.w = pkt(f1.z, f1.w);
      pl.x = pkt(l0, l1); pl.y = pkt(l2, l3);
      pl.z = pkt(l4, l5); pl.w = pkt(l6, l7);
    } else {
      pe = make_int4(0, 0, 0, 0); pl = pe;
    }
    int swg = (r * 128 + cb * 16) ^ ((r & 7) << 4);        // global slice (row r)
    int swl = (rloc * 128 + cb * 16) ^ ((rloc & 7) << 4);  // local tile (row rloc)
    *(int4*)(e16g + swg) = pe;
    *(int4*)((char*)LNE16 + swl) = pl;
  }
  __syncthreads();   // single wave: cheap; orders LDS writes before reads

  // ---- B-fragments straight from global w_ij (C2L folded) ----
  bf8 bw1[4][2], bw2[4][2];
#pragma unroll
  for (int n = 0; n < 4; ++n)
#pragma unroll
    for (int s = 0; s < 2; ++s) {
      const float* p1 = w_ij + (16 * n + c) * 192 + 8 * g + 32 * s;  // w1 cols
      const float* p2 = p1 + 64;                                      // w2 cols
      float4 a0 = *(const float4*)p1, a1 = *(const float4*)(p1 + 4);
      float4 q0 = *(const float4*)p2, q1 = *(const float4*)(p2 + 4);
      int4 pk;
      pk.x = pk2(a0.x * C2L, a0.y * C2L); pk.y = pk2(a0.z * C2L, a0.w * C2L);
      pk.z = pk2(a1.x * C2L, a1.y * C2L); pk.w = pk2(a1.z * C2L, a1.w * C2L);
      bw1[n][s] = *(bf8*)&pk;
      pk.x = pk2(q0.x * C2L, q0.y * C2L); pk.y = pk2(q0.z * C2L, q0.w * C2L);
      pk.z = pk2(q1.x * C2L, q1.y * C2L); pk.w = pk2(q1.z * C2L, q1.w * C2L);
      bw2[n][s] = *(bf8*)&pk;
    }

  // ---- PA/PB GEMM for this m-tile (A rows = local rloc = c) ----
  {
    bf8 a[2];
#pragma unroll
    for (int s = 0; s < 2; ++s)
      a[s] = *(bf8*)((char*)LNE16 + ((c * 128 + 16 * g + 64 * s) ^ ((c & 7) << 4)));
    f32x4 pa[4], pbk[4];
#pragma unroll
    for (int n = 0; n < 4; ++n) { pa[n] = (f32x4)0.f; pbk[n] = (f32x4)0.f; }
#pragma unroll
    for (int s = 0; s < 2; ++s)
#pragma unroll
      for (int n = 0; n < 4; ++n) {
        pa[n]  = __builtin_amdgcn_mfma_f32_16x16x32_bf16(a[s], bw1[n][s], pa[n], 0, 0, 0);
        pbk[n] = __builtin_amdgcn_mfma_f32_16x16x32_bf16(a[s], bw2[n][s], pbk[n], 0, 0, 0);
      }
#pragma unroll
    for (int reg = 0; reg < 4; ++reg) {
      int j = 16 * m + 4 * g + reg;
      uint2 v;
      v.x = (uint32_t)pk2(pa[0][reg], pa[1][reg]);
      v.y = (uint32_t)pk2(pa[2][reg], pa[3][reg]);
      *(uint2*)(pa16g + j * 128 + c * 8) = v;     // [j][x=c][n], no swizzle
      if (j < NI) {
#pragma unroll
        for (int n = 0; n < 4; ++n)
          pb16[(b * NI + j) * 64 + 16 * n + c] = (ushort)f2bf(pbk[n][reg]);
      }
    }
  }
}

// K2: one block per (b, 4-i tile); wave wv owns i = i0+wv end-to-end.
// XCD swizzle: b = bid & 63. Swapped-operand pass Q: Q[d][j], d on regs, j on lanes.
// Gram squares via in-register sq8t. (Byte-identical to R19's k2 at 45.5 us.)
__global__ __launch_bounds__(256, 3) void k2_main(
    const float* __restrict__ emb,
    const float* __restrict__ wsum,
    const float* __restrict__ bsum,
    const float* __restrict__ ws,
    float* __restrict__ out) {
  int bid = blockIdx.x;
  int b = bid & 63, itile = bid >> 6;
  int i0 = itile * IT;
  int tid = threadIdx.x;
  int wv = tid >> 6, lane = tid & 63, g = lane >> 4, c = lane & 15;
  int i = i0 + wv;

  __shared__ ushort E16[NIP * 64];   // 14336 B: bf16 e_j, swizzled
  __shared__ float rs2_s[IT][NIP];   // C2L*rs
  __shared__ float mrs2_s[IT][NIP];  // -C2L*mu*rs
  __shared__ float z_s[IT][NIP];     // z then alpha

  const char* e16g  = (const char*)ws + OFF_E16  * 4 + b * TILEB;
  const char* pa16g = (const char*)ws + OFF_PA16 * 4 + b * TILEB;
  const ushort* pb16 = (const ushort*)(ws + OFF_PB16);

  // stage E16 (linear copy; swizzle baked in)
  for (int u = tid; u < TILEB / 16; u += 256)
    ((int4*)E16)[u] = ((const int4*)e16g)[u];
  __syncthreads();

  // ---- Gram stats (squares in-register via sq8t) ----
  {
    bf8 aI[2], aIsq[2];
#pragma unroll
    for (int s = 0; s < 2; ++s) {
      int r = i0 + c;
      int sw = (r * 128 + 16 * g + 64 * s) ^ ((r & 7) << 4);
      aI[s]   = *(bf8*)((char*)E16 + sw);
      aIsq[s] = sq8t(aI[s]);
    }
    for (int jt = wv; jt < 7; jt += 4) {
      f32x4 g1 = (f32x4)0.f, g2 = (f32x4)0.f;
#pragma unroll
      for (int s = 0; s < 2; ++s) {
        int r = 16 * jt + c;
        int sw = (r * 128 + 16 * g + 64 * s) ^ ((r & 7) << 4);
        bf8 aj  = *(bf8*)((char*)E16 + sw);
        bf8 ajs = sq8t(aj);
        g1 = __builtin_amdgcn_mfma_f32_16x16x32_bf16(aI[s],   aj,  g1, 0, 0, 0);
        g2 = __builtin_amdgcn_mfma_f32_16x16x32_bf16(aIsq[s], ajs, g2, 0, 0, 0);
      }
      if (g == 0) {
#pragma unroll
        for (int reg = 0; reg < 4; ++reg) {
          float mu  = g1[reg] * (1.f / 64.f);
          float v2  = g2[reg] * (1.f / 64.f);
          float var = v2 - mu * mu;
          float rsv = rsqrtf(var + LN_EPS);
          rs2_s[reg][16 * jt + c]  = C2L * rsv;
          mrs2_s[reg][16 * jt + c] = -C2L * mu * rsv;
        }
      }
    }
  }

  // ---- bw3 fragments (e_i o w3g), A operand (rows = d) ----
  bf8 bw3[4][2];
  {
    const float* ei = emb + (b * NI + i) * 64;
    float4 eif[4];
#pragma unroll
    for (int s = 0; s < 2; ++s) {
      eif[2*s]   = *(const float4*)(ei + 8 * g + 32 * s);
      eif[2*s+1] = *(const float4*)(ei + 8 * g + 32 * s + 4);
    }
    const float* w3 = ws + OFF_W3GTT;
#pragma unroll
    for (int n = 0; n < 4; ++n) {
      int d = 16 * n + c;
#pragma unroll
      for (int s = 0; s < 2; ++s) {
        const float* wp = w3 + d * 64 + 8 * g + 32 * s;
        float4 w0 = *(const float4*)wp, w1v = *(const float4*)(wp + 4);
        float4 e0 = eif[2*s], e1 = eif[2*s+1];
        int4 pk;
        pk.x = pkt(w0.x * e0.x, w0.y * e0.y);
        pk.y = pkt(w0.z * e0.z, w0.w * e0.w);
        pk.z = pkt(w1v.x * e1.x, w1v.y * e1.y);
        pk.w = pkt(w1v.z * e1.z, w1v.w * e1.w);
        bw3[n][s] = *(bf8*)&pk;
      }
    }
  }

  // per-lane epilogue constants: d = 16n + 4g + reg
  float w3g_nr[4][4], cst2_nr[4][4], wsum_nr[4][4];
#pragma unroll
  for (int n = 0; n < 4; ++n) {
    int d0 = 16 * n + 4 * g;
    float4 wg  = *(const float4*)(ws + OFF_W3G + d0);
    float4 c0v = *(const float4*)(ws + OFF_C0 + d0);
    float4 wsv = *(const float4*)(wsum + d0);
    uint2 pbu = *(const uint2*)(pb16 + (b * NI + i) * 64 + d0);
    float pbf[4];
    pbf[0] = __uint_as_float(pbu.x << 16);
    pbf[1] = __uint_as_float(pbu.x & 0xffff0000u);
    pbf[2] = __uint_as_float(pbu.y << 16);
    pbf[3] = __uint_as_float(pbu.y & 0xffff0000u);
    w3g_nr[n][0] = wg.x;  w3g_nr[n][1] = wg.y;  w3g_nr[n][2] = wg.z;  w3g_nr[n][3] = wg.w;
    wsum_nr[n][0] = wsv.x; wsum_nr[n][1] = wsv.y; wsum_nr[n][2] = wsv.z; wsum_nr[n][3] = wsv.w;
    cst2_nr[n][0] = pbf[0] + c0v.x; cst2_nr[n][1] = pbf[1] + c0v.y;
    cst2_nr[n][2] = pbf[2] + c0v.z; cst2_nr[n][3] = pbf[3] + c0v.w;
  }
  float zbase = ws[OFF_WSUMS] + bsum[0];

  __syncthreads();   // rs2/mrs2 ready (cross-wave)

  // ---- pass Q (swapped): q3[n][reg] = Q[d=16n+4g+reg][j=16m+c] ----
  for (int m = 0; m < 7; ++m) {
    int jrow = 16 * m + c;
    int4 pa0 = *(const int4*)(pa16g + jrow * 128 + 32 * g);
    int4 pa1 = *(const int4*)(pa16g + jrow * 128 + 32 * g + 16);
    f32x4 q3[4];
#pragma unroll
    for (int n = 0; n < 4; ++n) q3[n] = (f32x4)0.f;
#pragma unroll
    for (int s = 0; s < 2; ++s) {
      int sw = (jrow * 128 + 16 * g + 64 * s) ^ ((jrow & 7) << 4);
      bf8 a = *(bf8*)((char*)E16 + sw);
#pragma unroll
      for (int n = 0; n < 4; ++n)
        q3[n] = __builtin_amdgcn_mfma_f32_16x16x32_bf16(bw3[n][s], a, q3[n], 0, 0, 0);
    }
    float rs2c  = rs2_s[wv][jrow];
    float mrs2c = mrs2_s[wv][jrow];
    uint32_t pw[4][2] = {{(uint32_t)pa0.x, (uint32_t)pa0.y},
                         {(uint32_t)pa0.z, (uint32_t)pa0.w},
                         {(uint32_t)pa1.x, (uint32_t)pa1.y},
                         {(uint32_t)pa1.z, (uint32_t)pa1.w}};
    float zacc0 = 0.f, zacc1 = 0.f;
#pragma unroll
    for (int reg = 0; reg < 4; ++reg) {
      float paf[4];
      paf[0] = __uint_as_float(pw[reg][0] << 16);
      paf[1] = __uint_as_float(pw[reg][0] & 0xffff0000u);
      paf[2] = __uint_as_float(pw[reg][1] << 16);
      paf[3] = __uint_as_float(pw[reg][1] & 0xffff0000u);
#pragma unroll
      for (int n = 0; n < 4; ++n) {
        float X = fmaf(rs2c, q3[n][reg],
                   fmaf(mrs2c, w3g_nr[n][reg], paf[n] + cst2_nr[n][reg]));
        float ex = fast_exp2(X);                      // e^{2x}
        float rr = __builtin_amdgcn_rcpf(ex + 1.f);   // tanh = 1 - 2*rr
        if (n & 1) zacc1 = fmaf(wsum_nr[n][reg], rr, zacc1);
        else       zacc0 = fmaf(wsum_nr[n][reg], rr, zacc0);
      }
    }
    float zacc = zacc0 + zacc1;
    zacc += __shfl_xor(zacc, 16, 64);
    zacc += __shfl_xor(zacc, 32, 64);
    if (g == 0)
      z_s[wv][jrow] = fmaf(-2.f, zacc, zbase);
  }

  // ---- softmax (per wave, own row) ----
  {
    int j0 = lane, j1 = lane + 64;
    bool v0 = (j0 != i);
    bool v1 = (j1 < NI) && (j1 != i);
    float z0 = z_s[wv][j0];
    float z1 = (j1 < NIP) ? z_s[wv][j1] : 0.f;
    z0 = v0 ? z0 : -__builtin_inff();
    z1 = v1 ? z1 : -__builtin_inff();
    float mx = fmaxf(z0, z1);
#pragma unroll
    for (int off = 32; off > 0; off >>= 1)
      mx = fmaxf(mx, __shfl_xor(mx, off, 64));
    float e0 = v0 ? __expf(z0 - mx) : 0.f;
    float e1 = v1 ? __expf(z1 - mx) : 0.f;
    float ss = e0 + e1;
#pragma unroll
    for (int off = 32; off > 0; off >>= 1)
      ss += __shfl_xor(ss, off, 64);
    float inv = __builtin_amdgcn_rcpf(ss);
    z_s[wv][j0] = e0 * inv;
    if (j1 < NIP) z_s[wv][j1] = e1 * inv;
  }

  // ---- PV: halves of 56 j's, static-XOR 8-unroll, float2 alpha reads ----
  {
    int kp = lane & 31, half = lane >> 5;
    int jb = half * 56;                 // z_s[100..111]=0, E16 rows 100..111 = 0
    float s0 = 0.f, s1 = 0.f, s0b = 0.f, s1b = 0.f;
#pragma unroll
    for (int t8 = 0; t8 < 56; t8 += 8) {
      int j0 = jb + t8;                 // multiple of 8
#pragma unroll
      for (int u = 0; u < 8; u += 2) {
        int j = j0 + u, j2 = j0 + u + 1;
        float2 al = *(const float2*)&z_s[wv][j];
        int sw  = (j  * 128 + kp * 4) ^ ((u & 7) << 4);          // XOR compile-time
        int sw2 = (j2 * 128 + kp * 4) ^ (((u + 1) & 7) << 4);
        uint32_t e0u = *(const uint32_t*)((const char*)E16 + sw);
        uint32_t e1u = *(const uint32_t*)((const char*)E16 + sw2);
        s0  = fmaf(al.x, __uint_as_float(e0u << 16), s0);
        s1  = fmaf(al.x, __uint_as_float(e0u & 0xffff0000u), s1);
        s0b = fmaf(al.y, __uint_as_float(e1u << 16), s0b);
        s1b = fmaf(al.y, __uint_as_float(e1u & 0xffff0000u), s1b);
      }
    }
    float sf0 = s0 + s0b, sf1 = s1 + s1b;
    sf0 += __shfl_xor(sf0, 32, 64);
    sf1 += __shfl_xor(sf1, 32, 64);
    if (half == 0) {
      const float* ei = emb + (b * NI + i) * 64;
      float e0 = ei[2 * kp], e1 = ei[2 * kp + 1];
      float c0 = fmaf(e0, sf0, e0 * e0);
      float c1 = fmaf(e1, sf1, e1 * e1);
      c0 = (c0 >= 0.f) ? c0 : 0.01f * c0;
      c1 = (c1 >= 0.f) ? c1 : 0.01f * c1;
      float2 o; o.x = c0; o.y = c1;
      *(float2*)(out + (b * NI + i) * 64 + 2 * kp) = o;
    }
  }
}

extern "C" void kernel_launch(void* const* d_in, const int* in_sizes, int n_in,
                              void* d_out, int out_size, void* d_ws, size_t ws_size,
                              hipStream_t stream) {
  const float* emb  = (const float*)d_in[0];
  const float* g    = (const float*)d_in[1];
  const float* bln  = (const float*)d_in[2];
  const float* w_ij = (const float*)d_in[3];
  const float* bij  = (const float*)d_in[4];
  const float* wsum = (const float*)d_in[5];
  const float* bsum = (const float*)d_in[6];
  float* ws  = (float*)d_ws;
  float* out = (float*)d_out;

  hipLaunchKernelGGL(k1_tile, dim3(BSZ * 7), dim3(64), 0, stream,
                     emb, g, bln, w_ij, bij, wsum, ws);
  hipLaunchKernelGGL(k2_main, dim3(BSZ * NT2), dim3(256), 0, stream,
                     emb, wsum, bsum, ws, out);
}